// Round 8
// baseline (189.587 us; speedup 1.0000x reference)
//
#include <hip/hip_runtime.h>
#include <hip/hip_bf16.h>

typedef unsigned short ushort_t;
typedef __bf16 bf16_t;
typedef bf16_t bf16x8 __attribute__((ext_vector_type(8)));
typedef float f32x4 __attribute__((ext_vector_type(4)));
typedef float f32x16 __attribute__((ext_vector_type(16)));

#define CH 512
#define NSP 1024  // H*W

__device__ __forceinline__ float bf2f(ushort_t u) {
    union { unsigned int i; float f; } t; t.i = ((unsigned int)u) << 16; return t.f;
}
__device__ __forceinline__ ushort_t f2bf(float f) {
    union { float fl; unsigned int i; } t; t.fl = f;
    unsigned int r = t.i + 0x7fffu + ((t.i >> 16) & 1u);  // RNE
    return (ushort_t)(r >> 16);
}
// packed RNE f32x2 -> bf16x2 (v_cvt_pk_bf16_f32 on gfx950)
__device__ __forceinline__ unsigned int pk2(float a, float b) {
    __hip_bfloat162 h = __float22bfloat162_rn(make_float2(a, b));
    union { __hip_bfloat162 h2; unsigned int u; } t; t.h2 = h; return t.u;
}

#if __has_builtin(__builtin_amdgcn_global_load_lds)
#define HAVE_ASYNC_LDS 1
#endif
__device__ __forceinline__ void cp16(const ushort_t* g, ushort_t* l) {
#ifdef HAVE_ASYNC_LDS
    __builtin_amdgcn_global_load_lds((const __attribute__((address_space(1))) unsigned int*)g,
                                     (__attribute__((address_space(3))) unsigned int*)l, 16, 0, 0);
#else
    *(uint4*)l = *(const uint4*)g;
#endif
}

#define QSCALE 0.18033688011112042f   // 0.125 * log2(e), folded into q

// ---------------- prep: blocks 0..255 = GN stats; 256..1279 = W fp32->bf16 ----------------
__global__ __launch_bounds__(256) void prep_kernel(const float* __restrict__ x,
                                                   const float* __restrict__ w0, const float* __restrict__ w1,
                                                   const float* __restrict__ w2, const float* __restrict__ w3,
                                                   float2* __restrict__ gstats, ushort_t* __restrict__ wbf) {
    int tid = threadIdx.x;
    if (blockIdx.x >= 256) {
        int idx = (blockIdx.x - 256) * 256 + tid;   // 0..262143 float4s
        int my = idx >> 16;
        const float* src = (my == 0) ? w0 : (my == 1) ? w1 : (my == 2) ? w2 : w3;
        float4 v = reinterpret_cast<const float4*>(src)[idx & 65535];
        uint2 u = make_uint2(pk2(v.x, v.y), pk2(v.z, v.w));
        reinterpret_cast<uint2*>(wbf + (size_t)my * 262144)[idx & 65535] = u;
        return;
    }
    __shared__ float red[8];
    int bg = blockIdx.x;
    size_t base = (size_t)bg * 16384;
    float s = 0.f, s2 = 0.f;
    const float4* x4 = reinterpret_cast<const float4*>(x + base);
    for (int i = tid; i < 4096; i += 256) {
        float4 v = x4[i];
        s  += v.x + v.y + v.z + v.w;
        s2 += v.x * v.x + v.y * v.y + v.z * v.z + v.w * v.w;
    }
    #pragma unroll
    for (int off = 32; off > 0; off >>= 1) {
        s  += __shfl_down(s, off, 64);
        s2 += __shfl_down(s2, off, 64);
    }
    int wv = tid >> 6;
    if ((tid & 63) == 0) { red[wv] = s; red[4 + wv] = s2; }
    __syncthreads();
    if (tid == 0) {
        float ts  = red[0] + red[1] + red[2] + red[3];
        float ts2 = red[4] + red[5] + red[6] + red[7];
        float mu  = ts * (1.f / 16384.f);
        float var = ts2 * (1.f / 16384.f) - mu * mu;
        gstats[bg] = make_float2(mu, rsqrtf(var + 1e-5f));
    }
}

// ---------------- GroupNorm apply + transpose -> xnt [b][n][c] bf16 ----------------
__global__ __launch_bounds__(256) void gn_apply(const float* __restrict__ x, const float* __restrict__ gw,
                                                const float* __restrict__ gbias, const float2* __restrict__ gstats,
                                                ushort_t* __restrict__ xnt) {
    __shared__ __align__(16) ushort_t lt[16 * 264];
    int nq = blockIdx.x;            // 0..3 (256-col chunk)
    int bg = blockIdx.y;            // b*32+g
    int b = bg >> 5, g = bg & 31;
    int tid = threadIdx.x;
    float2 st = gstats[bg];
    float mu = st.x, rstd = st.y;
    const float4* x4 = reinterpret_cast<const float4*>(x + ((size_t)(b * 512 + g * 16) * 1024 + nq * 256));
    #pragma unroll
    for (int rep = 0; rep < 4; rep++) {
        int id = rep * 256 + tid;
        int cc = id >> 6, j = id & 63;
        float ww = gw[g * 16 + cc], bb = gbias[g * 16 + cc];
        float ca = rstd * ww, cb = bb - mu * ca;
        float4 v = x4[cc * 256 + j];
        uint2 u = make_uint2(pk2(v.x * ca + cb, v.y * ca + cb), pk2(v.z * ca + cb, v.w * ca + cb));
        *reinterpret_cast<uint2*>(&lt[cc * 264 + j * 4]) = u;
    }
    __syncthreads();
    int n = tid;
    ushort_t ov[16];
    #pragma unroll
    for (int cc = 0; cc < 16; cc++) ov[cc] = lt[cc * 264 + n];
    ushort_t* dst = xnt + ((size_t)(b * 1024 + nq * 256 + n)) * 512 + g * 16;
    *reinterpret_cast<ushort4*>(dst + 0)  = *reinterpret_cast<ushort4*>(&ov[0]);
    *reinterpret_cast<ushort4*>(dst + 4)  = *reinterpret_cast<ushort4*>(&ov[4]);
    *reinterpret_cast<ushort4*>(dst + 8)  = *reinterpret_cast<ushort4*>(&ov[8]);
    *reinterpret_cast<ushort4*>(dst + 12) = *reinterpret_cast<ushort4*>(&ov[12]);
}

// ---------------- Fused QKV conv: C[n_sp(128)][o(64)] tiles, o in 0..1535 ----------------
__global__ __launch_bounds__(256) void conv_qkv(const ushort_t* __restrict__ xnt,
                                                const ushort_t* __restrict__ wbf,
                                                const float* __restrict__ bq,
                                                const float* __restrict__ bk,
                                                const float* __restrict__ bv,
                                                ushort_t* __restrict__ qt,
                                                ushort_t* __restrict__ kt,
                                                ushort_t* __restrict__ vt) {
    __shared__ __align__(16) char smem[17408];
    ushort_t* als = (ushort_t*)smem;           // [128][32]
    ushort_t* bls = (ushort_t*)(smem + 8192);  // [64][32]
    int tid = threadIdx.x;
    int wave = tid >> 6, lane = tid & 63, l15 = lane & 15, quad = lane >> 4;
    int wm = wave >> 1, wn = wave & 1;
    int m0 = blockIdx.x * 128, o0 = blockIdx.y * 64, b = blockIdx.z;
    const ushort_t* A = xnt + (size_t)b * 524288;

    f32x4 acc[4][2];
    #pragma unroll
    for (int ms = 0; ms < 4; ms++)
        #pragma unroll
        for (int ns = 0; ns < 2; ns++) acc[ms][ns] = (f32x4){0.f, 0.f, 0.f, 0.f};

    for (int k0 = 0; k0 < 512; k0 += 32) {
        #pragma unroll
        for (int rep = 0; rep < 2; rep++) {
            int id = rep * 256 + tid;
            int r = id >> 2, part = id & 3;
            int sw = part ^ ((r >> 2) & 3);
            cp16(A + (size_t)(m0 + r) * 512 + k0 + sw * 8, als + (size_t)id * 8);
        }
        {
            int r = tid >> 2, part = tid & 3;
            int sw = part ^ ((r >> 2) & 3);
            cp16(wbf + (size_t)(o0 + r) * 512 + k0 + sw * 8, bls + (size_t)tid * 8);
        }
        __syncthreads();
        bf16x8 af[4], bfr[2];
        #pragma unroll
        for (int ms = 0; ms < 4; ms++) {
            int row = wm * 64 + ms * 16 + l15;
            int slot = quad ^ ((row >> 2) & 3);
            af[ms] = *(const bf16x8*)(als + row * 32 + slot * 8);
        }
        #pragma unroll
        for (int ns = 0; ns < 2; ns++) {
            int row = wn * 32 + ns * 16 + l15;
            int slot = quad ^ ((row >> 2) & 3);
            bfr[ns] = *(const bf16x8*)(bls + row * 32 + slot * 8);
        }
        #pragma unroll
        for (int ms = 0; ms < 4; ms++)
            #pragma unroll
            for (int ns = 0; ns < 2; ns++)
                acc[ms][ns] = __builtin_amdgcn_mfma_f32_16x16x32_bf16(af[ms], bfr[ns], acc[ms][ns], 0, 0, 0);
        __syncthreads();
    }

    int seg = o0 >> 9, lo = o0 & 511;
    if (seg < 2) {
        const float* bias = seg ? bk : bq;
        ushort_t* dst = seg ? kt : qt;
        float s = seg ? 1.f : QSCALE;
        float bv0 = bias[lo + wn * 32 + l15];
        float bv1 = bias[lo + wn * 32 + 16 + l15];
        ushort_t* cls = (ushort_t*)smem;   // [128 n][64 o]
        #pragma unroll
        for (int ms = 0; ms < 4; ms++)
            #pragma unroll
            for (int ns = 0; ns < 2; ns++) {
                float bb = ns ? bv1 : bv0;
                int idx = (wm * 64 + ms * 16 + quad * 4) * 64 + wn * 32 + ns * 16 + l15;
                unsigned int ua = pk2((acc[ms][ns][0] + bb) * s, (acc[ms][ns][1] + bb) * s);
                unsigned int ub = pk2((acc[ms][ns][2] + bb) * s, (acc[ms][ns][3] + bb) * s);
                cls[idx]       = (ushort_t)(ua & 0xffff);
                cls[idx + 64]  = (ushort_t)(ua >> 16);
                cls[idx + 128] = (ushort_t)(ub & 0xffff);
                cls[idx + 192] = (ushort_t)(ub >> 16);
            }
        __syncthreads();
        int h = lo >> 6;
        size_t obase = ((size_t)(b * 8 + h) * 1024 + m0) * 64;
        #pragma unroll
        for (int rep = 0; rep < 4; rep++) {
            int id = rep * 256 + tid;
            int r = id >> 3, part = id & 7;
            *(uint4*)(dst + obase + (size_t)r * 64 + part * 8) = *(const uint4*)(cls + r * 64 + part * 8);
        }
    } else {
        float bv0 = bv[lo + wn * 32 + l15];
        float bv1 = bv[lo + wn * 32 + 16 + l15];
        ushort_t* clst = (ushort_t*)smem;  // [64 o][136] transposed
        #pragma unroll
        for (int ms = 0; ms < 4; ms++)
            #pragma unroll
            for (int ns = 0; ns < 2; ns++) {
                float bb = ns ? bv1 : bv0;
                unsigned int ua = pk2(acc[ms][ns][0] + bb, acc[ms][ns][1] + bb);
                unsigned int ub = pk2(acc[ms][ns][2] + bb, acc[ms][ns][3] + bb);
                *(uint2*)(&clst[(wn * 32 + ns * 16 + l15) * 136 + wm * 64 + ms * 16 + quad * 4]) =
                    make_uint2(ua, ub);
            }
        __syncthreads();
        #pragma unroll
        for (int rep = 0; rep < 4; rep++) {
            int id = rep * 256 + tid;
            int row = id >> 4, part = id & 15;
            *(uint4*)(vt + ((size_t)(b * 512 + lo + row) * 1024 + m0 + part * 8)) =
                *(const uint4*)(clst + row * 136 + part * 8);
        }
    }
}

// ---------------- MFMA flash attention v2: 32x32x16, frag-major LDS, slot-permuted V ----------------
// qt (pre-scaled)/kt: [bh][n][d]; vt: [bh][d][n]; ao: [b][n][c] bf16.
// 128 threads = 2 waves; i-tile 128 (64 i per wave as 2x 32); j-tiles of 64.
// K LDS frags: [frag=(j2*4+kc)][lane][16B]; elem e of lane l: K[32*j2 + (l&31)][16*kc + 8*(l>>5) + e].
// V LDS frags: [frag=(dt*4+jc)][lane][16B]; elem e: V[32*dt + (l&31)][16*jc + pi(8*(l>>5)+e)]
//   with pi(k) = (k&3) + 8*((k>>2)&1) + 4*(k>>3)  -- matches the 32x32 C-layout row order, so
//   exp'd S^T regs ARE the P A-fragments (no shuffle, no P LDS round-trip).
__global__ __launch_bounds__(128, 1) void attn_kernel(const ushort_t* __restrict__ qt,
                                                      const ushort_t* __restrict__ kt,
                                                      const ushort_t* __restrict__ vt,
                                                      ushort_t* __restrict__ ao) {
    __shared__ __align__(16) char smem[34816];
    ushort_t* kls = (ushort_t*)smem;             // 8 KB
    ushort_t* vls = (ushort_t*)(smem + 8192);    // 8 KB
    float* ofp  = (float*)smem;                  // epilogue: [128][66] f32 (33792 B)
    float* llds = (float*)(smem + 33792);        // 128 floats

    int tid = threadIdx.x;
    int w = tid >> 6, l = tid & 63;
    int l31 = l & 31, h = l >> 5;
    int id = blockIdx.x;
    int bh = (id & 7) * 8 + ((id >> 3) & 7);     // XCD-local bh slab
    int i0 = (id >> 6) * 128;
    const ushort_t* qb = qt + (size_t)bh * 65536;
    const ushort_t* kb = kt + (size_t)bh * 65536;
    const ushort_t* vb = vt + (size_t)bh * 65536;
    int iw = i0 + w * 64;

    // Q fragments (scaled upstream): qf[it2][kc], elem e: Q[iw+32*it2+(l&31)][16*kc+8*h+e]
    bf16x8 qf[2][4];
    #pragma unroll
    for (int it2 = 0; it2 < 2; it2++)
        #pragma unroll
        for (int kc = 0; kc < 4; kc++)
            qf[it2][kc] = *(const bf16x8*)(qb + (size_t)(iw + it2 * 32 + l31) * 64 + kc * 16 + h * 8);

    f32x16 oacc[2][2];   // [it2][dt]
    #pragma unroll
    for (int a = 0; a < 2; a++)
        #pragma unroll
        for (int b2 = 0; b2 < 2; b2++)
            #pragma unroll
            for (int r = 0; r < 16; r++) oacc[a][b2][r] = 0.f;
    float lacc[2] = {0.f, 0.f};

    // staging: K chunk ck=rep*128+tid -> (jr=ck>>3, dc=ck&7); V same -> (dr, c8)
    uint4 krg[4], vrg[4];
    #pragma unroll
    for (int rep = 0; rep < 4; rep++) {
        int ck = rep * 128 + tid;
        int jr = ck >> 3, dc = ck & 7;
        krg[rep] = *(const uint4*)(kb + (size_t)jr * 64 + dc * 8);
        vrg[rep] = *(const uint4*)(vb + (size_t)jr * 1024 + dc * 8);
    }

    for (int jt = 0; jt < 16; jt++) {
        if (jt) __syncthreads();
        #pragma unroll
        for (int rep = 0; rep < 4; rep++) {
            int ck = rep * 128 + tid;
            int jr = ck >> 3, dc = ck & 7;
            // K: frag (jr>>5)*4 + (dc>>1), lane (jr&31) + 32*(dc&1)
            int fa = ((jr >> 5) * 4 + (dc >> 1)) * 64 + (jr & 31) + 32 * (dc & 1);
            *(uint4*)(kls + fa * 8) = krg[rep];
            // V: frag (dr>>5)*4 + (c8>>1); halves go to lane-halves (pi split)
            int vbase = ((jr >> 5) * 4 + (dc >> 1)) * 64 + (jr & 31);
            int eg = dc & 1;
            *(uint2*)(vls + vbase * 8 + eg * 4)        = make_uint2(vrg[rep].x, vrg[rep].y);
            *(uint2*)(vls + (vbase + 32) * 8 + eg * 4) = make_uint2(vrg[rep].z, vrg[rep].w);
        }
        __syncthreads();
        if (jt < 15) {
            int j0n = (jt + 1) * 64;
            #pragma unroll
            for (int rep = 0; rep < 4; rep++) {
                int ck = rep * 128 + tid;
                int jr = ck >> 3, dc = ck & 7;
                krg[rep] = *(const uint4*)(kb + (size_t)(j0n + jr) * 64 + dc * 8);
                vrg[rep] = *(const uint4*)(vb + (size_t)jr * 1024 + j0n + dc * 8);
            }
        }

        bf16x8 kf[2][4];
        #pragma unroll
        for (int j2 = 0; j2 < 2; j2++)
            #pragma unroll
            for (int kc = 0; kc < 4; kc++)
                kf[j2][kc] = *(const bf16x8*)(kls + ((j2 * 4 + kc) * 64 + l) * 8);

        // S^T + exp + pack (regs are directly the P A-frags thanks to pi-layout of V)
        union Pk { unsigned int u[8]; bf16x8 f[2]; } pk[2][2];
        #pragma unroll
        for (int it2 = 0; it2 < 2; it2++)
            #pragma unroll
            for (int j2 = 0; j2 < 2; j2++) {
                f32x16 z;
                #pragma unroll
                for (int r = 0; r < 16; r++) z[r] = 0.f;
                #pragma unroll
                for (int kc = 0; kc < 4; kc++)
                    z = __builtin_amdgcn_mfma_f32_32x32x16_bf16(kf[j2][kc], qf[it2][kc], z, 0, 0, 0);
                float e[16];
                float sum = 0.f;
                #pragma unroll
                for (int r = 0; r < 16; r++) { e[r] = exp2f(z[r]); sum += e[r]; }
                lacc[it2] += sum;
                #pragma unroll
                for (int u = 0; u < 8; u++) pk[it2][j2].u[u] = pk2(e[2 * u], e[2 * u + 1]);
            }

        bf16x8 vf[2][4];
        #pragma unroll
        for (int dt = 0; dt < 2; dt++)
            #pragma unroll
            for (int jc = 0; jc < 4; jc++)
                vf[dt][jc] = *(const bf16x8*)(vls + ((dt * 4 + jc) * 64 + l) * 8);

        #pragma unroll
        for (int it2 = 0; it2 < 2; it2++)
            #pragma unroll
            for (int dt = 0; dt < 2; dt++)
                #pragma unroll
                for (int jc = 0; jc < 4; jc++)
                    oacc[it2][dt] = __builtin_amdgcn_mfma_f32_32x32x16_bf16(
                        pk[it2][jc >> 1].f[jc & 1], vf[dt][jc], oacc[it2][dt], 0, 0, 0);
    }

    lacc[0] += __shfl_xor(lacc[0], 32, 64);
    lacc[1] += __shfl_xor(lacc[1], 32, 64);
    __syncthreads();   // staging LDS reads done; reuse as f32 O buffer
    if (h == 0) {
        llds[w * 64 + l31]      = lacc[0];
        llds[w * 64 + 32 + l31] = lacc[1];
    }
    #pragma unroll
    for (int it2 = 0; it2 < 2; it2++)
        #pragma unroll
        for (int dt = 0; dt < 2; dt++)
            #pragma unroll
            for (int r = 0; r < 16; r++) {
                int row = w * 64 + it2 * 32 + (r & 3) + 8 * (r >> 2) + 4 * h;
                ofp[row * 66 + dt * 32 + l31] = oacc[it2][dt][r];
            }
    __syncthreads();
    float linv = 1.f / llds[tid];
    int bb = bh >> 3, hh = bh & 7;
    ushort_t* aob = ao + ((size_t)bb * 1024 + i0 + tid) * 512 + hh * 64;
    #pragma unroll
    for (int c = 0; c < 8; c++) {
        float2 a0 = *(const float2*)(ofp + tid * 66 + c * 8 + 0);
        float2 a1 = *(const float2*)(ofp + tid * 66 + c * 8 + 2);
        float2 a2 = *(const float2*)(ofp + tid * 66 + c * 8 + 4);
        float2 a3 = *(const float2*)(ofp + tid * 66 + c * 8 + 6);
        uint4 o;
        o.x = pk2(a0.x * linv, a0.y * linv);
        o.y = pk2(a1.x * linv, a1.y * linv);
        o.z = pk2(a2.x * linv, a2.y * linv);
        o.w = pk2(a3.x * linv, a3.y * linv);
        *(uint4*)(aob + c * 8) = o;
    }
}

// ---------------- Final conv: C[o(64)][n(64)] = Wo x ao + bo + x, fp32 out ----------------
__global__ __launch_bounds__(256) void conv_out(const ushort_t* __restrict__ ao,
                                                const ushort_t* __restrict__ wo,
                                                const float* __restrict__ bo,
                                                const float* __restrict__ xres,
                                                float* __restrict__ out) {
    __shared__ __align__(16) char smem[17408];
    ushort_t* als = (ushort_t*)smem;           // [64][32]
    ushort_t* bls = (ushort_t*)(smem + 4096);  // [64][32]
    int tid = threadIdx.x;
    int wave = tid >> 6, lane = tid & 63, l15 = lane & 15, quad = lane >> 4;
    int wm = wave >> 1, wn = wave & 1;
    int m0 = blockIdx.x * 64, n0 = blockIdx.y * 64, b = blockIdx.z;
    const ushort_t* B = ao + (size_t)b * 524288;

    f32x4 acc[2][2];
    #pragma unroll
    for (int ms = 0; ms < 2; ms++)
        #pragma unroll
        for (int ns = 0; ns < 2; ns++) acc[ms][ns] = (f32x4){0.f, 0.f, 0.f, 0.f};

    for (int k0 = 0; k0 < 512; k0 += 32) {
        {
            int r = tid >> 2, part = tid & 3;
            int sw = part ^ ((r >> 2) & 3);
            cp16(wo + (size_t)(m0 + r) * 512 + k0 + sw * 8, als + (size_t)tid * 8);
            cp16(B + (size_t)(n0 + r) * 512 + k0 + sw * 8, bls + (size_t)tid * 8);
        }
        __syncthreads();
        bf16x8 af[2], bfr[2];
        #pragma unroll
        for (int ms = 0; ms < 2; ms++) {
            int row = wm * 32 + ms * 16 + l15;
            int slot = quad ^ ((row >> 2) & 3);
            af[ms] = *(const bf16x8*)(als + row * 32 + slot * 8);
        }
        #pragma unroll
        for (int ns = 0; ns < 2; ns++) {
            int row = wn * 32 + ns * 16 + l15;
            int slot = quad ^ ((row >> 2) & 3);
            bfr[ns] = *(const bf16x8*)(bls + row * 32 + slot * 8);
        }
        #pragma unroll
        for (int ms = 0; ms < 2; ms++)
            #pragma unroll
            for (int ns = 0; ns < 2; ns++)
                acc[ms][ns] = __builtin_amdgcn_mfma_f32_16x16x32_bf16(af[ms], bfr[ns], acc[ms][ns], 0, 0, 0);
        __syncthreads();
    }

    float* clsf = (float*)smem;   // [64 o][68]
    #pragma unroll
    for (int ms = 0; ms < 2; ms++)
        #pragma unroll
        for (int ns = 0; ns < 2; ns++)
            #pragma unroll
            for (int r = 0; r < 4; r++)
                clsf[(wm * 32 + ms * 16 + quad * 4 + r) * 68 + wn * 32 + ns * 16 + l15] = acc[ms][ns][r];
    __syncthreads();
    #pragma unroll
    for (int rep = 0; rep < 4; rep++) {
        int id = rep * 256 + tid;
        int row = id >> 4, part = id & 15;
        float bvr = bo[m0 + row];
        float4 c4 = *(const float4*)(clsf + row * 68 + part * 4);
        size_t ga = ((size_t)(b * 512 + m0 + row)) * 1024 + n0 + part * 4;
        float4 xv = *(const float4*)(xres + ga);
        c4.x += bvr + xv.x; c4.y += bvr + xv.y; c4.z += bvr + xv.z; c4.w += bvr + xv.w;
        *(float4*)(out + ga) = c4;
    }
}

extern "C" void kernel_launch(void* const* d_in, const int* in_sizes, int n_in,
                              void* d_out, int out_size, void* d_ws, size_t ws_size,
                              hipStream_t stream) {
    const float* x    = (const float*)d_in[0];
    const float* gn_w = (const float*)d_in[1];
    const float* gn_b = (const float*)d_in[2];
    const float* wq   = (const float*)d_in[3];
    const float* bq   = (const float*)d_in[4];
    const float* wk   = (const float*)d_in[5];
    const float* bk   = (const float*)d_in[6];
    const float* wv   = (const float*)d_in[7];
    const float* bv   = (const float*)d_in[8];
    const float* wo   = (const float*)d_in[9];
    const float* bo   = (const float*)d_in[10];

    char* ws = (char*)d_ws;
    ushort_t* xnt  = (ushort_t*)(ws);                        // 8 MB  [b][n][c]
    ushort_t* qt   = (ushort_t*)(ws + (((size_t)8)  << 20)); // 8 MB  [bh][n][d] (pre-scaled)
    ushort_t* kt   = (ushort_t*)(ws + (((size_t)16) << 20)); // 8 MB  [bh][n][d]
    ushort_t* vt   = (ushort_t*)(ws + (((size_t)24) << 20)); // 8 MB  [b][c][n]
    ushort_t* wbf  = (ushort_t*)(ws + (((size_t)32) << 20)); // 2 MB  Wq|Wk|Wv|Wo bf16
    float2*   gst  = (float2*)  (ws + (((size_t)34) << 20)); // 2 KB  stats
    ushort_t* ao   = xnt;   // attn output reuses xnt

    prep_kernel<<<1280, 256, 0, stream>>>(x, wq, wk, wv, wo, gst, wbf);
    gn_apply<<<dim3(4, 256), 256, 0, stream>>>(x, gn_w, gn_b, gst, xnt);

    conv_qkv<<<dim3(8, 24, 8), 256, 0, stream>>>(xnt, wbf, bq, bk, bv, qt, kt, vt);

    attn_kernel<<<512, 128, 0, stream>>>(qt, kt, vt, ao);

    conv_out<<<dim3(8, 16, 8), 256, 0, stream>>>(ao, wbf + 786432, bo, x, (float*)d_out);
}

// Round 9
// 179.041 us; speedup vs baseline: 1.0589x; 1.0589x over previous
//
#include <hip/hip_runtime.h>
#include <hip/hip_bf16.h>

typedef unsigned short ushort_t;
typedef __bf16 bf16_t;
typedef bf16_t bf16x8 __attribute__((ext_vector_type(8)));
typedef float f32x4 __attribute__((ext_vector_type(4)));

#define CH 512
#define NSP 1024  // H*W

__device__ __forceinline__ float bf2f(ushort_t u) {
    union { unsigned int i; float f; } t; t.i = ((unsigned int)u) << 16; return t.f;
}
__device__ __forceinline__ ushort_t f2bf(float f) {
    union { float fl; unsigned int i; } t; t.fl = f;
    unsigned int r = t.i + 0x7fffu + ((t.i >> 16) & 1u);  // RNE
    return (ushort_t)(r >> 16);
}
// packed RNE f32x2 -> bf16x2 (v_cvt_pk_bf16_f32 on gfx950)
__device__ __forceinline__ unsigned int pk2(float a, float b) {
    __hip_bfloat162 h = __float22bfloat162_rn(make_float2(a, b));
    union { __hip_bfloat162 h2; unsigned int u; } t; t.h2 = h; return t.u;
}

#if __has_builtin(__builtin_amdgcn_global_load_lds)
#define HAVE_ASYNC_LDS 1
#endif
__device__ __forceinline__ void cp16(const ushort_t* g, ushort_t* l) {
#ifdef HAVE_ASYNC_LDS
    __builtin_amdgcn_global_load_lds((const __attribute__((address_space(1))) unsigned int*)g,
                                     (__attribute__((address_space(3))) unsigned int*)l, 16, 0, 0);
#else
    *(uint4*)l = *(const uint4*)g;
#endif
}

#define QSCALE 0.18033688011112042f   // 0.125 * log2(e), folded into q

// ---------------- prep: blocks 0..255 = GN stats; 256..1279 = W fp32->bf16 ----------------
__global__ __launch_bounds__(256) void prep_kernel(const float* __restrict__ x,
                                                   const float* __restrict__ w0, const float* __restrict__ w1,
                                                   const float* __restrict__ w2, const float* __restrict__ w3,
                                                   float2* __restrict__ gstats, ushort_t* __restrict__ wbf) {
    int tid = threadIdx.x;
    if (blockIdx.x >= 256) {
        int idx = (blockIdx.x - 256) * 256 + tid;   // 0..262143 float4s
        int my = idx >> 16;
        const float* src = (my == 0) ? w0 : (my == 1) ? w1 : (my == 2) ? w2 : w3;
        float4 v = reinterpret_cast<const float4*>(src)[idx & 65535];
        uint2 u = make_uint2(pk2(v.x, v.y), pk2(v.z, v.w));
        reinterpret_cast<uint2*>(wbf + (size_t)my * 262144)[idx & 65535] = u;
        return;
    }
    __shared__ float red[8];
    int bg = blockIdx.x;
    size_t base = (size_t)bg * 16384;
    float s = 0.f, s2 = 0.f;
    const float4* x4 = reinterpret_cast<const float4*>(x + base);
    for (int i = tid; i < 4096; i += 256) {
        float4 v = x4[i];
        s  += v.x + v.y + v.z + v.w;
        s2 += v.x * v.x + v.y * v.y + v.z * v.z + v.w * v.w;
    }
    #pragma unroll
    for (int off = 32; off > 0; off >>= 1) {
        s  += __shfl_down(s, off, 64);
        s2 += __shfl_down(s2, off, 64);
    }
    int wv = tid >> 6;
    if ((tid & 63) == 0) { red[wv] = s; red[4 + wv] = s2; }
    __syncthreads();
    if (tid == 0) {
        float ts  = red[0] + red[1] + red[2] + red[3];
        float ts2 = red[4] + red[5] + red[6] + red[7];
        float mu  = ts * (1.f / 16384.f);
        float var = ts2 * (1.f / 16384.f) - mu * mu;
        gstats[bg] = make_float2(mu, rsqrtf(var + 1e-5f));
    }
}

// ---------------- GroupNorm apply + transpose -> xnt [b][n][c] bf16 ----------------
__global__ __launch_bounds__(256) void gn_apply(const float* __restrict__ x, const float* __restrict__ gw,
                                                const float* __restrict__ gbias, const float2* __restrict__ gstats,
                                                ushort_t* __restrict__ xnt) {
    __shared__ __align__(16) ushort_t lt[16 * 264];
    int nq = blockIdx.x;            // 0..3 (256-col chunk)
    int bg = blockIdx.y;            // b*32+g
    int b = bg >> 5, g = bg & 31;
    int tid = threadIdx.x;
    float2 st = gstats[bg];
    float mu = st.x, rstd = st.y;
    const float4* x4 = reinterpret_cast<const float4*>(x + ((size_t)(b * 512 + g * 16) * 1024 + nq * 256));
    #pragma unroll
    for (int rep = 0; rep < 4; rep++) {
        int id = rep * 256 + tid;
        int cc = id >> 6, j = id & 63;
        float ww = gw[g * 16 + cc], bb = gbias[g * 16 + cc];
        float ca = rstd * ww, cb = bb - mu * ca;
        float4 v = x4[cc * 256 + j];
        uint2 u = make_uint2(pk2(v.x * ca + cb, v.y * ca + cb), pk2(v.z * ca + cb, v.w * ca + cb));
        *reinterpret_cast<uint2*>(&lt[cc * 264 + j * 4]) = u;
    }
    __syncthreads();
    int n = tid;
    ushort_t ov[16];
    #pragma unroll
    for (int cc = 0; cc < 16; cc++) ov[cc] = lt[cc * 264 + n];
    ushort_t* dst = xnt + ((size_t)(b * 1024 + nq * 256 + n)) * 512 + g * 16;
    *reinterpret_cast<ushort4*>(dst + 0)  = *reinterpret_cast<ushort4*>(&ov[0]);
    *reinterpret_cast<ushort4*>(dst + 4)  = *reinterpret_cast<ushort4*>(&ov[4]);
    *reinterpret_cast<ushort4*>(dst + 8)  = *reinterpret_cast<ushort4*>(&ov[8]);
    *reinterpret_cast<ushort4*>(dst + 12) = *reinterpret_cast<ushort4*>(&ov[12]);
}

// ---------------- Fused QKV conv: 128x128 tiles, batch-per-XCD swizzle ----------------
// id: b = id&7 (XCD), t = id>>3, mt = t/12, ot = t%12. C[m=n_sp(128)][o(128)].
// o<512 -> qt (scaled); <1024 -> kt; else vt[b][c][n] transposed.
__global__ __launch_bounds__(256) void conv_qkv(const ushort_t* __restrict__ xnt,
                                                const ushort_t* __restrict__ wbf,
                                                const float* __restrict__ bq,
                                                const float* __restrict__ bk,
                                                const float* __restrict__ bv,
                                                ushort_t* __restrict__ qt,
                                                ushort_t* __restrict__ kt,
                                                ushort_t* __restrict__ vt) {
    __shared__ __align__(16) char smem[34816];
    ushort_t* als = (ushort_t*)smem;           // [128][32] 8KB
    ushort_t* bls = (ushort_t*)(smem + 8192);  // [128][32] 8KB
    int tid = threadIdx.x;
    int wave = tid >> 6, lane = tid & 63, l15 = lane & 15, quad = lane >> 4;
    int wm = wave >> 1, wn = wave & 1;
    int id = blockIdx.x;
    int b = id & 7, t = id >> 3;
    int mt = t / 12, ot = t - mt * 12;
    int m0 = mt * 128, o0 = ot * 128;
    const ushort_t* A = xnt + (size_t)b * 524288;

    f32x4 acc[4][4];
    #pragma unroll
    for (int ms = 0; ms < 4; ms++)
        #pragma unroll
        for (int ns = 0; ns < 4; ns++) acc[ms][ns] = (f32x4){0.f, 0.f, 0.f, 0.f};

    for (int k0 = 0; k0 < 512; k0 += 32) {
        #pragma unroll
        for (int rep = 0; rep < 2; rep++) {
            int cid = rep * 256 + tid;
            int r = cid >> 2, part = cid & 3;
            int sw = part ^ ((r >> 2) & 3);
            cp16(A + (size_t)(m0 + r) * 512 + k0 + sw * 8, als + (size_t)cid * 8);
            cp16(wbf + (size_t)(o0 + r) * 512 + k0 + sw * 8, bls + (size_t)cid * 8);
        }
        __syncthreads();
        bf16x8 af[4], bfr[4];
        #pragma unroll
        for (int ms = 0; ms < 4; ms++) {
            int row = wm * 64 + ms * 16 + l15;
            int slot = quad ^ ((row >> 2) & 3);
            af[ms] = *(const bf16x8*)(als + row * 32 + slot * 8);
        }
        #pragma unroll
        for (int ns = 0; ns < 4; ns++) {
            int row = wn * 64 + ns * 16 + l15;
            int slot = quad ^ ((row >> 2) & 3);
            bfr[ns] = *(const bf16x8*)(bls + row * 32 + slot * 8);
        }
        #pragma unroll
        for (int ms = 0; ms < 4; ms++)
            #pragma unroll
            for (int ns = 0; ns < 4; ns++)
                acc[ms][ns] = __builtin_amdgcn_mfma_f32_16x16x32_bf16(af[ms], bfr[ns], acc[ms][ns], 0, 0, 0);
        __syncthreads();
    }

    int seg = o0 >> 9, lo = o0 & 511;
    if (seg < 2) {
        const float* bias = seg ? bk : bq;
        ushort_t* dst = seg ? kt : qt;
        float s = seg ? 1.f : QSCALE;
        float bvv[4];
        #pragma unroll
        for (int ns = 0; ns < 4; ns++) bvv[ns] = bias[lo + wn * 64 + ns * 16 + l15];
        ushort_t* cls = (ushort_t*)smem;   // [128 n][132]
        #pragma unroll
        for (int ms = 0; ms < 4; ms++)
            #pragma unroll
            for (int ns = 0; ns < 4; ns++) {
                int col = wn * 64 + ns * 16 + l15;
                int base = (wm * 64 + ms * 16 + quad * 4) * 132 + col;
                cls[base]           = f2bf((acc[ms][ns][0] + bvv[ns]) * s);
                cls[base + 132]     = f2bf((acc[ms][ns][1] + bvv[ns]) * s);
                cls[base + 264]     = f2bf((acc[ms][ns][2] + bvv[ns]) * s);
                cls[base + 396]     = f2bf((acc[ms][ns][3] + bvv[ns]) * s);
            }
        __syncthreads();
        int h0 = lo >> 6;
        #pragma unroll
        for (int rep = 0; rep < 8; rep++) {
            int cid = rep * 256 + tid;
            int row = cid >> 4, p = cid & 15;
            int h = h0 + (p >> 3);
            size_t ga = ((size_t)(b * 8 + h) * 1024 + m0 + row) * 64 + (p & 7) * 8;
            *(uint4*)(dst + ga) = *(const uint4*)(cls + row * 132 + p * 8);
        }
    } else {
        float bvv[4];
        #pragma unroll
        for (int ns = 0; ns < 4; ns++) bvv[ns] = bv[lo + wn * 64 + ns * 16 + l15];
        ushort_t* clst = (ushort_t*)smem;  // [128 o][132] transposed
        #pragma unroll
        for (int ms = 0; ms < 4; ms++)
            #pragma unroll
            for (int ns = 0; ns < 4; ns++) {
                unsigned int ua = pk2(acc[ms][ns][0] + bvv[ns], acc[ms][ns][1] + bvv[ns]);
                unsigned int ub = pk2(acc[ms][ns][2] + bvv[ns], acc[ms][ns][3] + bvv[ns]);
                *(uint2*)(&clst[(wn * 64 + ns * 16 + l15) * 132 + wm * 64 + ms * 16 + quad * 4]) =
                    make_uint2(ua, ub);
            }
        __syncthreads();
        #pragma unroll
        for (int rep = 0; rep < 8; rep++) {
            int cid = rep * 256 + tid;
            int row = cid >> 4, p = cid & 15;
            *(uint4*)(vt + ((size_t)(b * 512 + lo + row) * 1024 + m0 + p * 8)) =
                *(const uint4*)(clst + row * 132 + p * 8);
        }
    }
}

// ---------------- MFMA flash attention (round-7 version: 16x16, S^T trick, XCD swizzle) ----------------
__global__ __launch_bounds__(256) void attn_kernel(const ushort_t* __restrict__ qt,
                                                   const ushort_t* __restrict__ kt,
                                                   const ushort_t* __restrict__ vt,
                                                   ushort_t* __restrict__ ao) {
    __shared__ __align__(16) ushort_t kls[64 * 72];
    __shared__ __align__(16) ushort_t vls[64 * 72];
    __shared__ __align__(16) ushort_t pls[64 * 88];
    int tid = threadIdx.x;
    int wave = tid >> 6, lane = tid & 63, l15 = lane & 15, quad = lane >> 4;
    int id = blockIdx.x;
    int sub = id >> 3;
    int bh = (id & 7) * 8 + (sub >> 4);
    int i0 = (sub & 15) * 64;
    const ushort_t* qb = qt + (size_t)bh * 65536;
    const ushort_t* kb = kt + (size_t)bh * 65536;
    const ushort_t* vb = vt + (size_t)bh * 65536;
    int iw = wave * 16;

    bf16x8 qf0 = *(const bf16x8*)(qb + (size_t)(i0 + iw + l15) * 64 + quad * 8);
    bf16x8 qf1 = *(const bf16x8*)(qb + (size_t)(i0 + iw + l15) * 64 + 32 + quad * 8);

    f32x4 oacc[4];
    #pragma unroll
    for (int ds = 0; ds < 4; ds++) oacc[ds] = (f32x4){0.f, 0.f, 0.f, 0.f};
    float lacc = 0.f;

    int rl0 = tid >> 3, p0 = tid & 7;
    int rl1 = 32 + rl0;
    uint4 kr0 = *(const uint4*)(kb + (size_t)rl0 * 64 + p0 * 8);
    uint4 kr1 = *(const uint4*)(kb + (size_t)rl1 * 64 + p0 * 8);
    uint4 vr0 = *(const uint4*)(vb + (size_t)rl0 * 1024 + p0 * 8);
    uint4 vr1 = *(const uint4*)(vb + (size_t)rl1 * 1024 + p0 * 8);

    for (int jt = 0; jt < 16; jt++) {
        if (jt) __syncthreads();
        *(uint4*)(kls + rl0 * 72 + p0 * 8) = kr0;
        *(uint4*)(kls + rl1 * 72 + p0 * 8) = kr1;
        *(uint4*)(vls + rl0 * 72 + p0 * 8) = vr0;
        *(uint4*)(vls + rl1 * 72 + p0 * 8) = vr1;
        __syncthreads();
        if (jt < 15) {
            int j0n = (jt + 1) * 64;
            kr0 = *(const uint4*)(kb + (size_t)(j0n + rl0) * 64 + p0 * 8);
            kr1 = *(const uint4*)(kb + (size_t)(j0n + rl1) * 64 + p0 * 8);
            vr0 = *(const uint4*)(vb + (size_t)rl0 * 1024 + j0n + p0 * 8);
            vr1 = *(const uint4*)(vb + (size_t)rl1 * 1024 + j0n + p0 * 8);
        }

        #pragma unroll
        for (int js = 0; js < 4; js++) {
            bf16x8 kf0 = *(const bf16x8*)(kls + (js * 16 + l15) * 72 + quad * 8);
            bf16x8 kf1 = *(const bf16x8*)(kls + (js * 16 + l15) * 72 + 32 + quad * 8);
            f32x4 z = (f32x4){0.f, 0.f, 0.f, 0.f};
            z = __builtin_amdgcn_mfma_f32_16x16x32_bf16(kf0, qf0, z, 0, 0, 0);
            z = __builtin_amdgcn_mfma_f32_16x16x32_bf16(kf1, qf1, z, 0, 0, 0);
            float e0 = exp2f(z[0]), e1 = exp2f(z[1]), e2 = exp2f(z[2]), e3 = exp2f(z[3]);
            lacc += (e0 + e1) + (e2 + e3);
            *(uint2*)(pls + (iw + l15) * 88 + js * 16 + quad * 4) =
                make_uint2(pk2(e0, e1), pk2(e2, e3));
        }
        bf16x8 pa0 = *(const bf16x8*)(pls + (iw + l15) * 88 + quad * 8);
        bf16x8 pa1 = *(const bf16x8*)(pls + (iw + l15) * 88 + 32 + quad * 8);
        #pragma unroll
        for (int ds = 0; ds < 4; ds++) {
            bf16x8 vf0 = *(const bf16x8*)(vls + (ds * 16 + l15) * 72 + quad * 8);
            bf16x8 vf1 = *(const bf16x8*)(vls + (ds * 16 + l15) * 72 + 32 + quad * 8);
            oacc[ds] = __builtin_amdgcn_mfma_f32_16x16x32_bf16(pa0, vf0, oacc[ds], 0, 0, 0);
            oacc[ds] = __builtin_amdgcn_mfma_f32_16x16x32_bf16(pa1, vf1, oacc[ds], 0, 0, 0);
        }
    }

    lacc += __shfl_xor(lacc, 16, 64);
    lacc += __shfl_xor(lacc, 32, 64);
    float linv[4];
    #pragma unroll
    for (int r = 0; r < 4; r++) linv[r] = 1.f / __shfl(lacc, quad * 4 + r, 64);

    __syncthreads();
    #pragma unroll
    for (int ds = 0; ds < 4; ds++)
        #pragma unroll
        for (int r = 0; r < 4; r++)
            kls[(iw + quad * 4 + r) * 72 + ds * 16 + l15] = f2bf(oacc[ds][r] * linv[r]);
    __syncthreads();
    int b = bh >> 3, h = bh & 7;
    ushort_t* aob = ao + ((size_t)b * 1024 + i0) * 512 + h * 64;
    #pragma unroll
    for (int rep = 0; rep < 2; rep++) {
        int idd = rep * 256 + tid;
        int rl = idd >> 3, part = idd & 7;
        *(uint4*)(aob + (size_t)rl * 512 + part * 8) = *(const uint4*)(kls + rl * 72 + part * 8);
    }
}

// ---------------- Final conv: 128x64 tiles, batch-per-XCD. C[o(128)][n(64)] = Wo x ao + bo + x ----------------
__global__ __launch_bounds__(256) void conv_out(const ushort_t* __restrict__ ao,
                                                const ushort_t* __restrict__ wo,
                                                const float* __restrict__ bo,
                                                const float* __restrict__ xres,
                                                float* __restrict__ out) {
    __shared__ __align__(16) char smem[34816];
    ushort_t* als = (ushort_t*)smem;           // [128][32] Wo rows o
    ushort_t* bls = (ushort_t*)(smem + 8192);  // [64][32]  ao rows n
    int tid = threadIdx.x;
    int wave = tid >> 6, lane = tid & 63, l15 = lane & 15, quad = lane >> 4;
    int wm = wave >> 1, wn = wave & 1;
    int id = blockIdx.x;
    int b = id & 7, t = id >> 3;
    int mt = t >> 4, nt = t & 15;
    int m0 = mt * 128, n0 = nt * 64;
    const ushort_t* B = ao + (size_t)b * 524288;

    f32x4 acc[4][2];
    #pragma unroll
    for (int ms = 0; ms < 4; ms++)
        #pragma unroll
        for (int ns = 0; ns < 2; ns++) acc[ms][ns] = (f32x4){0.f, 0.f, 0.f, 0.f};

    for (int k0 = 0; k0 < 512; k0 += 32) {
        #pragma unroll
        for (int rep = 0; rep < 2; rep++) {
            int cid = rep * 256 + tid;
            int r = cid >> 2, part = cid & 3;
            int sw = part ^ ((r >> 2) & 3);
            cp16(wo + (size_t)(m0 + r) * 512 + k0 + sw * 8, als + (size_t)cid * 8);
        }
        {
            int r = tid >> 2, part = tid & 3;
            int sw = part ^ ((r >> 2) & 3);
            cp16(B + (size_t)(n0 + r) * 512 + k0 + sw * 8, bls + (size_t)tid * 8);
        }
        __syncthreads();
        bf16x8 af[4], bfr[2];
        #pragma unroll
        for (int ms = 0; ms < 4; ms++) {
            int row = wm * 64 + ms * 16 + l15;
            int slot = quad ^ ((row >> 2) & 3);
            af[ms] = *(const bf16x8*)(als + row * 32 + slot * 8);
        }
        #pragma unroll
        for (int ns = 0; ns < 2; ns++) {
            int row = wn * 32 + ns * 16 + l15;
            int slot = quad ^ ((row >> 2) & 3);
            bfr[ns] = *(const bf16x8*)(bls + row * 32 + slot * 8);
        }
        #pragma unroll
        for (int ms = 0; ms < 4; ms++)
            #pragma unroll
            for (int ns = 0; ns < 2; ns++)
                acc[ms][ns] = __builtin_amdgcn_mfma_f32_16x16x32_bf16(af[ms], bfr[ns], acc[ms][ns], 0, 0, 0);
        __syncthreads();
    }

    float* clsf = (float*)smem;   // [128 o][66] f32
    #pragma unroll
    for (int ms = 0; ms < 4; ms++)
        #pragma unroll
        for (int ns = 0; ns < 2; ns++)
            #pragma unroll
            for (int r = 0; r < 4; r++)
                clsf[(wm * 64 + ms * 16 + quad * 4 + r) * 66 + wn * 32 + ns * 16 + l15] = acc[ms][ns][r];
    __syncthreads();
    #pragma unroll
    for (int rep = 0; rep < 8; rep++) {
        int cid = rep * 256 + tid;
        int row = cid >> 4, p = cid & 15;
        float bvr = bo[m0 + row];
        float4 c4 = *(const float4*)(clsf + row * 66 + p * 4);
        size_t ga = ((size_t)(b * 512 + m0 + row)) * 1024 + n0 + p * 4;
        float4 xv = *(const float4*)(xres + ga);
        c4.x += bvr + xv.x; c4.y += bvr + xv.y; c4.z += bvr + xv.z; c4.w += bvr + xv.w;
        *(float4*)(out + ga) = c4;
    }
}

extern "C" void kernel_launch(void* const* d_in, const int* in_sizes, int n_in,
                              void* d_out, int out_size, void* d_ws, size_t ws_size,
                              hipStream_t stream) {
    const float* x    = (const float*)d_in[0];
    const float* gn_w = (const float*)d_in[1];
    const float* gn_b = (const float*)d_in[2];
    const float* wq   = (const float*)d_in[3];
    const float* bq   = (const float*)d_in[4];
    const float* wk   = (const float*)d_in[5];
    const float* bk   = (const float*)d_in[6];
    const float* wv   = (const float*)d_in[7];
    const float* bv   = (const float*)d_in[8];
    const float* wo   = (const float*)d_in[9];
    const float* bo   = (const float*)d_in[10];

    char* ws = (char*)d_ws;
    ushort_t* xnt  = (ushort_t*)(ws);                        // 8 MB  [b][n][c]
    ushort_t* qt   = (ushort_t*)(ws + (((size_t)8)  << 20)); // 8 MB  [bh][n][d] (pre-scaled)
    ushort_t* kt   = (ushort_t*)(ws + (((size_t)16) << 20)); // 8 MB  [bh][n][d]
    ushort_t* vt   = (ushort_t*)(ws + (((size_t)24) << 20)); // 8 MB  [b][c][n]
    ushort_t* wbf  = (ushort_t*)(ws + (((size_t)32) << 20)); // 2 MB  Wq|Wk|Wv|Wo bf16
    float2*   gst  = (float2*)  (ws + (((size_t)34) << 20)); // 2 KB  stats
    ushort_t* ao   = xnt;   // attn output reuses xnt

    prep_kernel<<<1280, 256, 0, stream>>>(x, wq, wk, wv, wo, gst, wbf);
    gn_apply<<<dim3(4, 256), 256, 0, stream>>>(x, gn_w, gn_b, gst, xnt);

    conv_qkv<<<768, 256, 0, stream>>>(xnt, wbf, bq, bk, bv, qt, kt, vt);

    attn_kernel<<<1024, 256, 0, stream>>>(qt, kt, vt, ao);

    conv_out<<<512, 256, 0, stream>>>(ao, wbf + 786432, bo, x, (float*)d_out);
}